// Round 2
// baseline (540.923 us; speedup 1.0000x reference)
//
#include <hip/hip_runtime.h>
#include <math.h>

typedef unsigned int u32;
typedef long long i64;

#define BINS 256

// ---------------- helpers ----------------

// Bit-exact replica of the float32 numpy pipeline:
//   normalized = (|x| / mv) * 8            (f32; *8 exact)
//   clipped    = min(normalized, 8.0f)     (clip bound 7.99999999 casts to 8.0f)
//   idx        = int(clipped / 8 * 255)    (/8 exact -> min(|x|/mv,1)*255, f32 mul, trunc)
__device__ __forceinline__ int bin_index_f32(float xv, float mv) {
    float r = __fdiv_rn(fabsf(xv), mv);   // IEEE f32 division
    r = fminf(r, 1.0f);
    return (int)__fmul_rn(r, 255.0f);     // in [0,255]
}

// ---------------- level-1 radix histogram (bits 31..21, sign cleared -> 1024 bins) ----------------

__global__ __launch_bounds__(256) void k_hist_l1(const float* __restrict__ x, u32* __restrict__ histA, i64 nper) {
    __shared__ u32 lh[8][1025];
    const int c = blockIdx.y;
    for (int i = threadIdx.x; i < 8 * 1025; i += blockDim.x) (&lh[0][0])[i] = 0;
    __syncthreads();
    const float* xc = x + (i64)c * nper;
    const i64 nv = nper >> 2;
    const int copy = threadIdx.x & 7;
    const float4* xv = (const float4*)xc;
    for (i64 i = (i64)blockIdx.x * blockDim.x + threadIdx.x; i < nv; i += (i64)gridDim.x * blockDim.x) {
        float4 v = xv[i];
        atomicAdd(&lh[copy][__float_as_uint(fabsf(v.x)) >> 21], 1u);
        atomicAdd(&lh[copy][__float_as_uint(fabsf(v.y)) >> 21], 1u);
        atomicAdd(&lh[copy][__float_as_uint(fabsf(v.z)) >> 21], 1u);
        atomicAdd(&lh[copy][__float_as_uint(fabsf(v.w)) >> 21], 1u);
    }
    if (blockIdx.x == 0 && threadIdx.x < (int)(nper & 3)) {
        float v = xc[nv * 4 + threadIdx.x];
        atomicAdd(&lh[copy][__float_as_uint(fabsf(v)) >> 21], 1u);
    }
    __syncthreads();
    for (int i = threadIdx.x; i < 1024; i += blockDim.x) {
        u32 s = 0;
#pragma unroll
        for (int k = 0; k < 8; ++k) s += lh[k][i];
        if (s) atomicAdd(&histA[c * 1024 + i], s);
    }
}

__global__ void k_scan_l1(const u32* __restrict__ histA, u32* __restrict__ sel, i64 k0, int C) {
    int c = threadIdx.x;
    if (c >= C) return;
    const u32* h = histA + c * 1024;
    i64 t0 = k0, t1 = k0 + 1, cum = 0;
    u32 p0 = 0, r0 = 0, p1 = 0, r1 = 0; int f0 = 0, f1 = 0;
    for (int b = 0; b < 1024 && !(f0 && f1); ++b) {
        u32 cnt = h[b];
        if (!f0 && cum + (i64)cnt > t0) { p0 = (u32)b; r0 = (u32)(t0 - cum); f0 = 1; }
        if (!f1 && cum + (i64)cnt > t1) { p1 = (u32)b; r1 = (u32)(t1 - cum); f1 = 1; }
        cum += cnt;
    }
    sel[c * 4 + 0] = p0; sel[c * 4 + 1] = r0; sel[c * 4 + 2] = p1; sel[c * 4 + 3] = r1;
}

// ---------------- level-2 (bits 20..10, 2048 bins), two chains ----------------

__global__ __launch_bounds__(256) void k_hist_l2(const float* __restrict__ x, const u32* __restrict__ sel,
                                                 u32* __restrict__ hB0, u32* __restrict__ hB1, i64 nper) {
    __shared__ u32 lh0[2048], lh1[2048];
    const int c = blockIdx.y;
    const u32 p0 = sel[c * 4 + 0], p1 = sel[c * 4 + 2];
    const bool two = (p1 != p0);
    for (int i = threadIdx.x; i < 2048; i += blockDim.x) { lh0[i] = 0; lh1[i] = 0; }
    __syncthreads();
    const float* xc = x + (i64)c * nper;
    const i64 nv = nper >> 2;
    const float4* xv = (const float4*)xc;
    for (i64 i = (i64)blockIdx.x * blockDim.x + threadIdx.x; i < nv; i += (i64)gridDim.x * blockDim.x) {
        float4 v = xv[i];
        u32 b;
        b = __float_as_uint(fabsf(v.x));
        if ((b >> 21) == p0) atomicAdd(&lh0[(b >> 10) & 2047], 1u);
        else if (two && (b >> 21) == p1) atomicAdd(&lh1[(b >> 10) & 2047], 1u);
        b = __float_as_uint(fabsf(v.y));
        if ((b >> 21) == p0) atomicAdd(&lh0[(b >> 10) & 2047], 1u);
        else if (two && (b >> 21) == p1) atomicAdd(&lh1[(b >> 10) & 2047], 1u);
        b = __float_as_uint(fabsf(v.z));
        if ((b >> 21) == p0) atomicAdd(&lh0[(b >> 10) & 2047], 1u);
        else if (two && (b >> 21) == p1) atomicAdd(&lh1[(b >> 10) & 2047], 1u);
        b = __float_as_uint(fabsf(v.w));
        if ((b >> 21) == p0) atomicAdd(&lh0[(b >> 10) & 2047], 1u);
        else if (two && (b >> 21) == p1) atomicAdd(&lh1[(b >> 10) & 2047], 1u);
    }
    if (blockIdx.x == 0 && threadIdx.x < (int)(nper & 3)) {
        u32 b = __float_as_uint(fabsf(xc[nv * 4 + threadIdx.x]));
        if ((b >> 21) == p0) atomicAdd(&lh0[(b >> 10) & 2047], 1u);
        else if (two && (b >> 21) == p1) atomicAdd(&lh1[(b >> 10) & 2047], 1u);
    }
    __syncthreads();
    for (int i = threadIdx.x; i < 2048; i += blockDim.x) {
        if (lh0[i]) atomicAdd(&hB0[c * 2048 + i], lh0[i]);
        if (two && lh1[i]) atomicAdd(&hB1[c * 2048 + i], lh1[i]);
    }
}

__global__ void k_scan_l2(const u32* __restrict__ hB0, const u32* __restrict__ hB1, u32* __restrict__ sel, int C) {
    int c = threadIdx.x;
    if (c >= C) return;
    u32 p0 = sel[c * 4 + 0], r0 = sel[c * 4 + 1], p1 = sel[c * 4 + 2], r1 = sel[c * 4 + 3];
    const u32* h0 = hB0 + c * 2048;
    const u32* h1 = (p1 == p0) ? h0 : (hB1 + c * 2048);
    {
        i64 cum = 0;
        for (int b = 0; b < 2048; ++b) { u32 cnt = h0[b]; if (cum + (i64)cnt > (i64)r0) { sel[c * 4 + 0] = (p0 << 11) | (u32)b; sel[c * 4 + 1] = (u32)((i64)r0 - cum); break; } cum += cnt; }
    }
    {
        i64 cum = 0;
        for (int b = 0; b < 2048; ++b) { u32 cnt = h1[b]; if (cum + (i64)cnt > (i64)r1) { sel[c * 4 + 2] = (p1 << 11) | (u32)b; sel[c * 4 + 3] = (u32)((i64)r1 - cum); break; } cum += cnt; }
    }
}

// ---------------- level-3 (bits 9..0, 1024 bins), two chains ----------------

__global__ __launch_bounds__(256) void k_hist_l3(const float* __restrict__ x, const u32* __restrict__ sel,
                                                 u32* __restrict__ hC0, u32* __restrict__ hC1, i64 nper) {
    __shared__ u32 lh0[1024], lh1[1024];
    const int c = blockIdx.y;
    const u32 p0 = sel[c * 4 + 0], p1 = sel[c * 4 + 2];
    const bool two = (p1 != p0);
    for (int i = threadIdx.x; i < 1024; i += blockDim.x) { lh0[i] = 0; lh1[i] = 0; }
    __syncthreads();
    const float* xc = x + (i64)c * nper;
    const i64 nv = nper >> 2;
    const float4* xv = (const float4*)xc;
    for (i64 i = (i64)blockIdx.x * blockDim.x + threadIdx.x; i < nv; i += (i64)gridDim.x * blockDim.x) {
        float4 v = xv[i];
        u32 b;
        b = __float_as_uint(fabsf(v.x));
        if ((b >> 10) == p0) atomicAdd(&lh0[b & 1023], 1u);
        else if (two && (b >> 10) == p1) atomicAdd(&lh1[b & 1023], 1u);
        b = __float_as_uint(fabsf(v.y));
        if ((b >> 10) == p0) atomicAdd(&lh0[b & 1023], 1u);
        else if (two && (b >> 10) == p1) atomicAdd(&lh1[b & 1023], 1u);
        b = __float_as_uint(fabsf(v.z));
        if ((b >> 10) == p0) atomicAdd(&lh0[b & 1023], 1u);
        else if (two && (b >> 10) == p1) atomicAdd(&lh1[b & 1023], 1u);
        b = __float_as_uint(fabsf(v.w));
        if ((b >> 10) == p0) atomicAdd(&lh0[b & 1023], 1u);
        else if (two && (b >> 10) == p1) atomicAdd(&lh1[b & 1023], 1u);
    }
    if (blockIdx.x == 0 && threadIdx.x < (int)(nper & 3)) {
        u32 b = __float_as_uint(fabsf(xc[nv * 4 + threadIdx.x]));
        if ((b >> 10) == p0) atomicAdd(&lh0[b & 1023], 1u);
        else if (two && (b >> 10) == p1) atomicAdd(&lh1[b & 1023], 1u);
    }
    __syncthreads();
    for (int i = threadIdx.x; i < 1024; i += blockDim.x) {
        if (lh0[i]) atomicAdd(&hC0[c * 1024 + i], lh0[i]);
        if (two && lh1[i]) atomicAdd(&hC1[c * 1024 + i], lh1[i]);
    }
}

// ---------------- finalize: exact order stats -> f32 numpy lerp -> max_vals (f32) ----------------

__global__ void k_finalize(const u32* __restrict__ hC0, const u32* __restrict__ hC1,
                           const u32* __restrict__ sel, float* __restrict__ mv,
                           double gamma, int C) {
    int c = threadIdx.x;
    if (c >= C) return;
    u32 p0 = sel[c * 4 + 0], r0 = sel[c * 4 + 1], p1 = sel[c * 4 + 2], r1 = sel[c * 4 + 3];
    const u32* h0 = hC0 + c * 1024;
    const u32* h1 = (p1 == p0) ? h0 : (hC1 + c * 1024);
    u32 v0bits = 0, v1bits = 0;
    {
        i64 cum = 0;
        for (int b = 0; b < 1024; ++b) { u32 cnt = h0[b]; if (cum + (i64)cnt > (i64)r0) { v0bits = (p0 << 10) | (u32)b; break; } cum += cnt; }
    }
    {
        i64 cum = 0;
        for (int b = 0; b < 1024; ++b) { u32 cnt = h1[b]; if (cum + (i64)cnt > (i64)r1) { v1bits = (p1 << 10) | (u32)b; break; } cum += cnt; }
    }
    float v0 = __uint_as_float(v0bits);
    float v1 = __uint_as_float(v1bits);
    // numpy float32 _lerp: diff in f32, scalar (1-t)/t cast to f32, no FMA contraction
    float dba = __fsub_rn(v1, v0);
    float q;
    if (gamma >= 0.5) q = __fsub_rn(v1, __fmul_rn(dba, (float)(1.0 - gamma)));
    else              q = __fadd_rn(v0, __fmul_rn(dba, (float)gamma));
    mv[c] = fmaxf(q, 1e-8f);   // np.maximum(quantile, EPS), f32
}

// ---------------- 256-bin index histogram ----------------

__global__ __launch_bounds__(256) void k_hist_idx(const float* __restrict__ x, const float* __restrict__ mv,
                                                  u32* __restrict__ h256, i64 nper) {
    __shared__ u32 lh[8][257];
    const int c = blockIdx.y;
    const float m = mv[c];
    for (int i = threadIdx.x; i < 8 * 257; i += blockDim.x) (&lh[0][0])[i] = 0;
    __syncthreads();
    const float* xc = x + (i64)c * nper;
    const i64 nv = nper >> 2;
    const int copy = threadIdx.x & 7;
    const float4* xv = (const float4*)xc;
    for (i64 i = (i64)blockIdx.x * blockDim.x + threadIdx.x; i < nv; i += (i64)gridDim.x * blockDim.x) {
        float4 v = xv[i];
        atomicAdd(&lh[copy][bin_index_f32(v.x, m)], 1u);
        atomicAdd(&lh[copy][bin_index_f32(v.y, m)], 1u);
        atomicAdd(&lh[copy][bin_index_f32(v.z, m)], 1u);
        atomicAdd(&lh[copy][bin_index_f32(v.w, m)], 1u);
    }
    if (blockIdx.x == 0 && threadIdx.x < (int)(nper & 3)) {
        atomicAdd(&lh[copy][bin_index_f32(xc[nv * 4 + threadIdx.x], m)], 1u);
    }
    __syncthreads();
    for (int i = threadIdx.x; i < BINS; i += blockDim.x) {
        u32 s = 0;
#pragma unroll
        for (int k = 0; k < 8; ++k) s += lh[k][i];
        if (s) atomicAdd(&h256[c * BINS + i], s);
    }
}

// ---------------- mask table: mask[c][b] = sigmoid(-(Lam - THRESH)) ----------------

__global__ void k_mask_table(const float* __restrict__ hist_in, const float* __restrict__ logp_ref,
                             const u32* __restrict__ h256, double* __restrict__ mask) {
    __shared__ double sm[BINS];
    __shared__ double ssum;
    const int c = blockIdx.x;
    const int b = threadIdx.x;  // 256 threads
    // EMA with separately-rounded f32 ops, matching numpy ufunc-by-ufunc rounding
    float h = hist_in[c * BINS + b];
    float n = (float)h256[c * BINS + b];
    float t = __fadd_rn(__fmul_rn(0.98f, h), __fmul_rn(0.02f, n));
    float smf = __fadd_rn(t, 1e-8f);
    double smoothed = (double)smf;
    sm[b] = smoothed;
    __syncthreads();
    if (b == 0) { double s = 0.0; for (int i = 0; i < BINS; ++i) s += sm[i]; ssum = s; }
    __syncthreads();
    double logp_obs = log(smoothed / ssum);
    double Lam = (double)logp_ref[c * BINS + b] - logp_obs;
    mask[c * BINS + b] = 1.0 / (1.0 + exp(Lam + 2.0));   // THRESH = -2
}

// ---------------- output: out = x * mask[c][idx] ----------------

__global__ __launch_bounds__(256) void k_output(const float* __restrict__ x, const float* __restrict__ mv,
                                                const double* __restrict__ mask, float* __restrict__ out, i64 nper) {
    const int c = blockIdx.y;
    const float m = mv[c];
    const double* mt = mask + c * BINS;
    const float* xc = x + (i64)c * nper;
    float* oc = out + (i64)c * nper;
    const i64 nv = nper >> 2;
    const float4* xv = (const float4*)xc;
    float4* ov = (float4*)oc;
    for (i64 i = (i64)blockIdx.x * blockDim.x + threadIdx.x; i < nv; i += (i64)gridDim.x * blockDim.x) {
        float4 v = xv[i];
        float4 o;
        o.x = (float)((double)v.x * mt[bin_index_f32(v.x, m)]);
        o.y = (float)((double)v.y * mt[bin_index_f32(v.y, m)]);
        o.z = (float)((double)v.z * mt[bin_index_f32(v.z, m)]);
        o.w = (float)((double)v.w * mt[bin_index_f32(v.w, m)]);
        ov[i] = o;
    }
    if (blockIdx.x == 0 && threadIdx.x < (int)(nper & 3)) {
        i64 i = nv * 4 + threadIdx.x;
        float v = xc[i];
        oc[i] = (float)((double)v * mt[bin_index_f32(v, m)]);
    }
}

// ---------------- launch ----------------

extern "C" void kernel_launch(void* const* d_in, const int* in_sizes, int n_in,
                              void* d_out, int out_size, void* d_ws, size_t ws_size,
                              hipStream_t stream) {
    const float* x        = (const float*)d_in[0];
    const float* hist_in  = (const float*)d_in[1];
    const float* logp_ref = (const float*)d_in[2];
    float* out = (float*)d_out;

    const int C = in_sizes[1] / BINS;            // 5
    const i64 total = (i64)in_sizes[0];
    const i64 nper = total / C;                  // B*L = 8388608

    // workspace layout (all offsets 8-byte aligned)
    char* w = (char*)d_ws;
    size_t off = 0;
    float*  mv   = (float*)(w + off);  off += 8 * C;
    double* mask = (double*)(w + off); off += 8 * BINS * C;
    u32* histA = (u32*)(w + off); off += 4 * 1024 * C;
    u32* hB0   = (u32*)(w + off); off += 4 * 2048 * C;
    u32* hB1   = (u32*)(w + off); off += 4 * 2048 * C;
    u32* hC0   = (u32*)(w + off); off += 4 * 1024 * C;
    u32* hC1   = (u32*)(w + off); off += 4 * 1024 * C;
    u32* h256  = (u32*)(w + off); off += 4 * BINS * C;
    u32* sel   = (u32*)(w + off); off += 4 * 4 * C;

    hipMemsetAsync(d_ws, 0, off, stream);

    const double virt = 0.99 * (double)(nper - 1);
    const i64 k0 = (i64)floor(virt);
    const double gamma = virt - (double)k0;

    dim3 blk(256);
    dim3 grd(512, (unsigned)C);

    k_hist_l1<<<grd, blk, 0, stream>>>(x, histA, nper);
    k_scan_l1<<<1, 64, 0, stream>>>(histA, sel, k0, C);
    k_hist_l2<<<grd, blk, 0, stream>>>(x, sel, hB0, hB1, nper);
    k_scan_l2<<<1, 64, 0, stream>>>(hB0, hB1, sel, C);
    k_hist_l3<<<grd, blk, 0, stream>>>(x, sel, hC0, hC1, nper);
    k_finalize<<<1, 64, 0, stream>>>(hC0, hC1, sel, mv, gamma, C);
    k_hist_idx<<<grd, blk, 0, stream>>>(x, mv, h256, nper);
    k_mask_table<<<(unsigned)C, BINS, 0, stream>>>(hist_in, logp_ref, h256, mask);
    k_output<<<grd, blk, 0, stream>>>(x, mv, mask, out, nper);
}

// Round 3
// 250.946 us; speedup vs baseline: 2.1555x; 2.1555x over previous
//
#include <hip/hip_runtime.h>
#include <math.h>

typedef unsigned int u32;
typedef long long i64;

#define BINS 256

// ---------------- helpers ----------------

// Bit-exact replica of the float32 numpy pipeline:
//   normalized = (|x| / mv) * 8            (f32; *8 exact)
//   clipped    = min(normalized, 8.0f)     (clip bound 7.99999999 casts to 8.0f)
//   idx        = int(clipped / 8 * 255)    (/8 exact -> min(|x|/mv,1)*255, f32 mul, trunc)
__device__ __forceinline__ int bin_index_f32(float xv, float mv) {
    float r = __fdiv_rn(fabsf(xv), mv);   // IEEE f32 division
    r = fminf(r, 1.0f);
    return (int)__fmul_rn(r, 255.0f);     // in [0,255]
}

// Parallel rank-select over h[0..nb) for `target`; exactly one thread writes
// res[0]=bucket, res[1]=target-cum_exclusive(bucket). 256 threads, nb in {1024,2048}.
// ssum: 256-entry LDS scratch. Caller must __syncthreads() between calls.
__device__ void block_select(const u32* __restrict__ h, int nb, u32 target,
                             u32* ssum, u32* res) {
    const int t = threadIdx.x;
    const int per = nb >> 8;
    u32 loc[8];
    u32 s = 0;
    const int base = t * per;
    for (int j = 0; j < per; ++j) { loc[j] = h[base + j]; s += loc[j]; }
    ssum[t] = s;
    __syncthreads();
    for (int off = 1; off < 256; off <<= 1) {
        u32 add = (t >= off) ? ssum[t - off] : 0;
        __syncthreads();
        ssum[t] += add;
        __syncthreads();
    }
    u32 cum = ssum[t] - s;   // exclusive prefix of this thread's chunk
    for (int j = 0; j < per; ++j) {
        u32 cnt = loc[j];
        if (target >= cum && target < cum + cnt) { res[0] = (u32)(base + j); res[1] = target - cum; }
        cum += cnt;
    }
    __syncthreads();
}

// ---------------- level-1 radix histogram (bits 31..21, sign cleared -> 1024 bins) ----------------

__global__ __launch_bounds__(256) void k_hist_l1(const float* __restrict__ x, u32* __restrict__ histA, i64 nper) {
    __shared__ u32 lh[8][1025];
    const int c = blockIdx.y;
    for (int i = threadIdx.x; i < 8 * 1025; i += blockDim.x) (&lh[0][0])[i] = 0;
    __syncthreads();
    const float* xc = x + (i64)c * nper;
    const i64 nv = nper >> 2;
    const int copy = threadIdx.x & 7;
    const float4* xv = (const float4*)xc;
    for (i64 i = (i64)blockIdx.x * blockDim.x + threadIdx.x; i < nv; i += (i64)gridDim.x * blockDim.x) {
        float4 v = xv[i];
        atomicAdd(&lh[copy][__float_as_uint(fabsf(v.x)) >> 21], 1u);
        atomicAdd(&lh[copy][__float_as_uint(fabsf(v.y)) >> 21], 1u);
        atomicAdd(&lh[copy][__float_as_uint(fabsf(v.z)) >> 21], 1u);
        atomicAdd(&lh[copy][__float_as_uint(fabsf(v.w)) >> 21], 1u);
    }
    if (blockIdx.x == 0 && threadIdx.x < (int)(nper & 3)) {
        float v = xc[nv * 4 + threadIdx.x];
        atomicAdd(&lh[copy][__float_as_uint(fabsf(v)) >> 21], 1u);
    }
    __syncthreads();
    for (int i = threadIdx.x; i < 1024; i += blockDim.x) {
        u32 s = 0;
#pragma unroll
        for (int k = 0; k < 8; ++k) s += lh[k][i];
        if (s) atomicAdd(&histA[c * 1024 + i], s);
    }
}

__global__ __launch_bounds__(256) void k_scan_l1(const u32* __restrict__ histA, u32* __restrict__ sel1,
                                                 u32 k0, int C) {
    __shared__ u32 ssum[256];
    __shared__ u32 pr[4];
    const int c = blockIdx.x;
    const u32* h = histA + c * 1024;
    block_select(h, 1024, k0, ssum, &pr[0]);
    block_select(h, 1024, k0 + 1, ssum, &pr[2]);
    if (threadIdx.x == 0) {
        sel1[c * 4 + 0] = pr[0]; sel1[c * 4 + 1] = pr[1];
        sel1[c * 4 + 2] = pr[2]; sel1[c * 4 + 3] = pr[3];
    }
}

// ---------------- level-2 (bits 20..10, 2048 bins), two chains ----------------

__global__ __launch_bounds__(256) void k_hist_l2(const float* __restrict__ x, const u32* __restrict__ sel1,
                                                 u32* __restrict__ hB0, u32* __restrict__ hB1, i64 nper) {
    __shared__ u32 lh0[2048], lh1[2048];
    const int c = blockIdx.y;
    const u32 p0 = sel1[c * 4 + 0], p1 = sel1[c * 4 + 2];
    const bool two = (p1 != p0);
    for (int i = threadIdx.x; i < 2048; i += blockDim.x) { lh0[i] = 0; lh1[i] = 0; }
    __syncthreads();
    const float* xc = x + (i64)c * nper;
    const i64 nv = nper >> 2;
    const float4* xv = (const float4*)xc;
    for (i64 i = (i64)blockIdx.x * blockDim.x + threadIdx.x; i < nv; i += (i64)gridDim.x * blockDim.x) {
        float4 v = xv[i];
        u32 b;
        b = __float_as_uint(fabsf(v.x));
        if ((b >> 21) == p0) atomicAdd(&lh0[(b >> 10) & 2047], 1u);
        else if (two && (b >> 21) == p1) atomicAdd(&lh1[(b >> 10) & 2047], 1u);
        b = __float_as_uint(fabsf(v.y));
        if ((b >> 21) == p0) atomicAdd(&lh0[(b >> 10) & 2047], 1u);
        else if (two && (b >> 21) == p1) atomicAdd(&lh1[(b >> 10) & 2047], 1u);
        b = __float_as_uint(fabsf(v.z));
        if ((b >> 21) == p0) atomicAdd(&lh0[(b >> 10) & 2047], 1u);
        else if (two && (b >> 21) == p1) atomicAdd(&lh1[(b >> 10) & 2047], 1u);
        b = __float_as_uint(fabsf(v.w));
        if ((b >> 21) == p0) atomicAdd(&lh0[(b >> 10) & 2047], 1u);
        else if (two && (b >> 21) == p1) atomicAdd(&lh1[(b >> 10) & 2047], 1u);
    }
    if (blockIdx.x == 0 && threadIdx.x < (int)(nper & 3)) {
        u32 b = __float_as_uint(fabsf(xc[nv * 4 + threadIdx.x]));
        if ((b >> 21) == p0) atomicAdd(&lh0[(b >> 10) & 2047], 1u);
        else if (two && (b >> 21) == p1) atomicAdd(&lh1[(b >> 10) & 2047], 1u);
    }
    __syncthreads();
    for (int i = threadIdx.x; i < 2048; i += blockDim.x) {
        if (lh0[i]) atomicAdd(&hB0[c * 2048 + i], lh0[i]);
        if (two && lh1[i]) atomicAdd(&hB1[c * 2048 + i], lh1[i]);
    }
}

__global__ __launch_bounds__(256) void k_scan_l2(const u32* __restrict__ hB0, const u32* __restrict__ hB1,
                                                 const u32* __restrict__ sel1, u32* __restrict__ sel2, int C) {
    __shared__ u32 ssum[256];
    __shared__ u32 pr[4];
    const int c = blockIdx.x;
    const u32 p0 = sel1[c * 4 + 0], r0 = sel1[c * 4 + 1], p1 = sel1[c * 4 + 2], r1 = sel1[c * 4 + 3];
    const u32* h0 = hB0 + c * 2048;
    const u32* h1 = (p1 == p0) ? h0 : (hB1 + c * 2048);
    block_select(h0, 2048, r0, ssum, &pr[0]);
    block_select(h1, 2048, r1, ssum, &pr[2]);
    if (threadIdx.x == 0) {
        sel2[c * 4 + 0] = (p0 << 11) | pr[0]; sel2[c * 4 + 1] = pr[1];
        sel2[c * 4 + 2] = (p1 << 11) | pr[2]; sel2[c * 4 + 3] = pr[3];
    }
}

// ---------------- level-3 (bits 9..0, 1024 bins), two chains ----------------

__global__ __launch_bounds__(256) void k_hist_l3(const float* __restrict__ x, const u32* __restrict__ sel2,
                                                 u32* __restrict__ hC0, u32* __restrict__ hC1, i64 nper) {
    __shared__ u32 lh0[1024], lh1[1024];
    const int c = blockIdx.y;
    const u32 p0 = sel2[c * 4 + 0], p1 = sel2[c * 4 + 2];
    const bool two = (p1 != p0);
    for (int i = threadIdx.x; i < 1024; i += blockDim.x) { lh0[i] = 0; lh1[i] = 0; }
    __syncthreads();
    const float* xc = x + (i64)c * nper;
    const i64 nv = nper >> 2;
    const float4* xv = (const float4*)xc;
    for (i64 i = (i64)blockIdx.x * blockDim.x + threadIdx.x; i < nv; i += (i64)gridDim.x * blockDim.x) {
        float4 v = xv[i];
        u32 b;
        b = __float_as_uint(fabsf(v.x));
        if ((b >> 10) == p0) atomicAdd(&lh0[b & 1023], 1u);
        else if (two && (b >> 10) == p1) atomicAdd(&lh1[b & 1023], 1u);
        b = __float_as_uint(fabsf(v.y));
        if ((b >> 10) == p0) atomicAdd(&lh0[b & 1023], 1u);
        else if (two && (b >> 10) == p1) atomicAdd(&lh1[b & 1023], 1u);
        b = __float_as_uint(fabsf(v.z));
        if ((b >> 10) == p0) atomicAdd(&lh0[b & 1023], 1u);
        else if (two && (b >> 10) == p1) atomicAdd(&lh1[b & 1023], 1u);
        b = __float_as_uint(fabsf(v.w));
        if ((b >> 10) == p0) atomicAdd(&lh0[b & 1023], 1u);
        else if (two && (b >> 10) == p1) atomicAdd(&lh1[b & 1023], 1u);
    }
    if (blockIdx.x == 0 && threadIdx.x < (int)(nper & 3)) {
        u32 b = __float_as_uint(fabsf(xc[nv * 4 + threadIdx.x]));
        if ((b >> 10) == p0) atomicAdd(&lh0[b & 1023], 1u);
        else if (two && (b >> 10) == p1) atomicAdd(&lh1[b & 1023], 1u);
    }
    __syncthreads();
    for (int i = threadIdx.x; i < 1024; i += blockDim.x) {
        if (lh0[i]) atomicAdd(&hC0[c * 1024 + i], lh0[i]);
        if (two && lh1[i]) atomicAdd(&hC1[c * 1024 + i], lh1[i]);
    }
}

// ---------------- finalize: exact order stats -> f32 numpy lerp -> max_vals (f32) ----------------

__global__ __launch_bounds__(256) void k_finalize(const u32* __restrict__ hC0, const u32* __restrict__ hC1,
                                                  const u32* __restrict__ sel2, float* __restrict__ mv,
                                                  double gamma, int C) {
    __shared__ u32 ssum[256];
    __shared__ u32 pr[4];
    const int c = blockIdx.x;
    const u32 p0 = sel2[c * 4 + 0], r0 = sel2[c * 4 + 1], p1 = sel2[c * 4 + 2], r1 = sel2[c * 4 + 3];
    const u32* h0 = hC0 + c * 1024;
    const u32* h1 = (p1 == p0) ? h0 : (hC1 + c * 1024);
    block_select(h0, 1024, r0, ssum, &pr[0]);
    block_select(h1, 1024, r1, ssum, &pr[2]);
    if (threadIdx.x == 0) {
        u32 v0bits = (p0 << 10) | pr[0];
        u32 v1bits = (p1 << 10) | pr[2];
        float v0 = __uint_as_float(v0bits);
        float v1 = __uint_as_float(v1bits);
        // numpy float32 _lerp: diff in f32, scalar (1-t)/t cast to f32, no FMA contraction
        float dba = __fsub_rn(v1, v0);
        float q;
        if (gamma >= 0.5) q = __fsub_rn(v1, __fmul_rn(dba, (float)(1.0 - gamma)));
        else              q = __fadd_rn(v0, __fmul_rn(dba, (float)gamma));
        mv[c] = fmaxf(q, 1e-8f);   // np.maximum(quantile, EPS), f32
    }
}

// ---------------- 256-bin index histogram ----------------

__global__ __launch_bounds__(256) void k_hist_idx(const float* __restrict__ x, const float* __restrict__ mv,
                                                  u32* __restrict__ h256, i64 nper) {
    __shared__ u32 lh[8][257];
    const int c = blockIdx.y;
    const float m = mv[c];
    for (int i = threadIdx.x; i < 8 * 257; i += blockDim.x) (&lh[0][0])[i] = 0;
    __syncthreads();
    const float* xc = x + (i64)c * nper;
    const i64 nv = nper >> 2;
    const int copy = threadIdx.x & 7;
    const float4* xv = (const float4*)xc;
    for (i64 i = (i64)blockIdx.x * blockDim.x + threadIdx.x; i < nv; i += (i64)gridDim.x * blockDim.x) {
        float4 v = xv[i];
        atomicAdd(&lh[copy][bin_index_f32(v.x, m)], 1u);
        atomicAdd(&lh[copy][bin_index_f32(v.y, m)], 1u);
        atomicAdd(&lh[copy][bin_index_f32(v.z, m)], 1u);
        atomicAdd(&lh[copy][bin_index_f32(v.w, m)], 1u);
    }
    if (blockIdx.x == 0 && threadIdx.x < (int)(nper & 3)) {
        atomicAdd(&lh[copy][bin_index_f32(xc[nv * 4 + threadIdx.x], m)], 1u);
    }
    __syncthreads();
    for (int i = threadIdx.x; i < BINS; i += blockDim.x) {
        u32 s = 0;
#pragma unroll
        for (int k = 0; k < 8; ++k) s += lh[k][i];
        if (s) atomicAdd(&h256[c * BINS + i], s);
    }
}

// ---------------- mask table: mask[c][b] = sigmoid(-(Lam - THRESH)) ----------------

__global__ void k_mask_table(const float* __restrict__ hist_in, const float* __restrict__ logp_ref,
                             const u32* __restrict__ h256, double* __restrict__ mask) {
    __shared__ double sm[BINS];
    __shared__ double ssum;
    const int c = blockIdx.x;
    const int b = threadIdx.x;  // 256 threads
    // EMA with separately-rounded f32 ops, matching numpy ufunc-by-ufunc rounding
    float h = hist_in[c * BINS + b];
    float n = (float)h256[c * BINS + b];
    float t = __fadd_rn(__fmul_rn(0.98f, h), __fmul_rn(0.02f, n));
    float smf = __fadd_rn(t, 1e-8f);
    double smoothed = (double)smf;
    sm[b] = smoothed;
    __syncthreads();
    if (b == 0) { double s = 0.0; for (int i = 0; i < BINS; ++i) s += sm[i]; ssum = s; }
    __syncthreads();
    double logp_obs = log(smoothed / ssum);
    double Lam = (double)logp_ref[c * BINS + b] - logp_obs;
    mask[c * BINS + b] = 1.0 / (1.0 + exp(Lam + 2.0));   // THRESH = -2
}

// ---------------- output: out = x * mask[c][idx] ----------------

__global__ __launch_bounds__(256) void k_output(const float* __restrict__ x, const float* __restrict__ mv,
                                                const double* __restrict__ mask, float* __restrict__ out, i64 nper) {
    const int c = blockIdx.y;
    const float m = mv[c];
    const double* mt = mask + c * BINS;
    const float* xc = x + (i64)c * nper;
    float* oc = out + (i64)c * nper;
    const i64 nv = nper >> 2;
    const float4* xv = (const float4*)xc;
    float4* ov = (float4*)oc;
    for (i64 i = (i64)blockIdx.x * blockDim.x + threadIdx.x; i < nv; i += (i64)gridDim.x * blockDim.x) {
        float4 v = xv[i];
        float4 o;
        o.x = (float)((double)v.x * mt[bin_index_f32(v.x, m)]);
        o.y = (float)((double)v.y * mt[bin_index_f32(v.y, m)]);
        o.z = (float)((double)v.z * mt[bin_index_f32(v.z, m)]);
        o.w = (float)((double)v.w * mt[bin_index_f32(v.w, m)]);
        ov[i] = o;
    }
    if (blockIdx.x == 0 && threadIdx.x < (int)(nper & 3)) {
        i64 i = nv * 4 + threadIdx.x;
        float v = xc[i];
        oc[i] = (float)((double)v * mt[bin_index_f32(v, m)]);
    }
}

// ---------------- launch ----------------

extern "C" void kernel_launch(void* const* d_in, const int* in_sizes, int n_in,
                              void* d_out, int out_size, void* d_ws, size_t ws_size,
                              hipStream_t stream) {
    const float* x        = (const float*)d_in[0];
    const float* hist_in  = (const float*)d_in[1];
    const float* logp_ref = (const float*)d_in[2];
    float* out = (float*)d_out;

    const int C = in_sizes[1] / BINS;            // 5
    const i64 total = (i64)in_sizes[0];
    const i64 nper = total / C;                  // B*L = 8388608

    // workspace layout (all offsets 8-byte aligned)
    char* w = (char*)d_ws;
    size_t off = 0;
    float*  mv   = (float*)(w + off);  off += 8 * C;
    double* mask = (double*)(w + off); off += 8 * BINS * C;
    u32* histA = (u32*)(w + off); off += 4 * 1024 * C;
    u32* hB0   = (u32*)(w + off); off += 4 * 2048 * C;
    u32* hB1   = (u32*)(w + off); off += 4 * 2048 * C;
    u32* hC0   = (u32*)(w + off); off += 4 * 1024 * C;
    u32* hC1   = (u32*)(w + off); off += 4 * 1024 * C;
    u32* h256  = (u32*)(w + off); off += 4 * BINS * C;
    u32* sel1  = (u32*)(w + off); off += 4 * 4 * C;
    u32* sel2  = (u32*)(w + off); off += 4 * 4 * C;

    hipMemsetAsync(d_ws, 0, off, stream);

    const double virt = 0.99 * (double)(nper - 1);
    const i64 k0 = (i64)floor(virt);
    const double gamma = virt - (double)k0;

    dim3 blk(256);
    dim3 grd(512, (unsigned)C);

    k_hist_l1<<<grd, blk, 0, stream>>>(x, histA, nper);
    k_scan_l1<<<(unsigned)C, blk, 0, stream>>>(histA, sel1, (u32)k0, C);
    k_hist_l2<<<grd, blk, 0, stream>>>(x, sel1, hB0, hB1, nper);
    k_scan_l2<<<(unsigned)C, blk, 0, stream>>>(hB0, hB1, sel1, sel2, C);
    k_hist_l3<<<grd, blk, 0, stream>>>(x, sel2, hC0, hC1, nper);
    k_finalize<<<(unsigned)C, blk, 0, stream>>>(hC0, hC1, sel2, mv, gamma, C);
    k_hist_idx<<<grd, blk, 0, stream>>>(x, mv, h256, nper);
    k_mask_table<<<(unsigned)C, BINS, 0, stream>>>(hist_in, logp_ref, h256, mask);
    k_output<<<grd, blk, 0, stream>>>(x, mv, mask, out, nper);
}